// Round 1
// baseline (292.860 us; speedup 1.0000x reference)
//
#include <hip/hip_runtime.h>

typedef __fp16 half2_t __attribute__((ext_vector_type(2)));

#define D 128
#define LN_EPS 1e-5f
#define BUCKET_NODES 128
#define BUCKET_SHIFT 7
#define EDGE_CAP 4096          // avg ~2046 edges/bucket, sigma ~45; 45-sigma headroom
#define FUSE_THREADS 512
#define K2_EPT 16              // 8192 edges per fill block
#define GT 512                 // gather block threads (8 waves -> all blocks co-resident)

// split-f16 packing: word f of a row holds (feat f, feat f+64) as packed f16
__device__ inline unsigned pack_h2(float a, float b) {
    half2_t p = __builtin_amdgcn_cvt_pkrtz(a, b);
    return __builtin_bit_cast(unsigned, p);
}

// ---- K1: stitched  conv (x f32 -> xb split-f16)  +  coarse bucket fill ----
__global__ __launch_bounds__(FUSE_THREADS)
void conv_fill_kernel(const float* __restrict__ x, unsigned int* __restrict__ xb,
                      int nwords, int conv_blocks,
                      const int* __restrict__ src, const int* __restrict__ dst,
                      const float* __restrict__ val,
                      int* __restrict__ gcnt, uint2* __restrict__ edges,
                      int E, int nbuckets) {
    if ((int)blockIdx.x < conv_blocks) {
        int i = blockIdx.x * FUSE_THREADS + threadIdx.x;
        if (i < nwords) {
            int node = i >> 6, f = i & 63;
            xb[i] = pack_h2(x[(size_t)node * D + f], x[(size_t)node * D + 64 + f]);
        }
        return;
    }
    // fill: per-block LDS hist -> one reservation atomic per bucket ->
    // per-block contiguous write runs (line-dense)
    __shared__ int lcnt[1024];
    __shared__ int lbase[1024];
    int fb = (int)blockIdx.x - conv_blocks;
    for (int i = threadIdx.x; i < nbuckets; i += FUSE_THREADS) lcnt[i] = 0;
    __syncthreads();

    int base = fb * (FUSE_THREADS * K2_EPT);
    unsigned int w0[K2_EPT];
    float        w1[K2_EPT];
    int          br[K2_EPT];   // (bucket<<16)|rank, or -1
    #pragma unroll
    for (int r = 0; r < K2_EPT; ++r) {
        int e = base + r * FUSE_THREADS + threadIdx.x;
        if (e < E) {
            int d = dst[e];
            int b = d >> BUCKET_SHIFT;
            int rk = atomicAdd(&lcnt[b], 1);
            w0[r] = (unsigned)src[e] | ((unsigned)(d & (BUCKET_NODES - 1)) << 20);
            w1[r] = val[e];
            br[r] = (b << 16) | rk;
        } else {
            br[r] = -1;
        }
    }
    __syncthreads();
    for (int i = threadIdx.x; i < nbuckets; i += FUSE_THREADS) {
        int c = lcnt[i];
        lbase[i] = c ? atomicAdd(&gcnt[i], c) : 0;
    }
    __syncthreads();
    #pragma unroll
    for (int r = 0; r < K2_EPT; ++r) {
        if (br[r] >= 0) {
            int b  = br[r] >> 16;
            int rk = br[r] & 0xffff;
            edges[(size_t)b * EDGE_CAP + lbase[b] + rk] =
                make_uint2(w0[r], __float_as_uint(w1[r]));
        }
    }
}

// ---- K2: block per bucket: LDS counting-sort + gather + diag-w + LN (+ReLU) ----
// 16-lane group = one node (4 nodes/wave). Lane sl covers feats
// {4sl..4sl+3} u {64+4sl..64+4sl+3} via split-f16 uint4 row loads.
// 8-wave blocks: 782 blocks * 8 waves = 6256 waves <= 8192 slots -> fully
// co-resident grid, no second scheduling round / tail.
__global__ __launch_bounds__(GT, 8)
void gather_ln_kernel(const uint4* __restrict__ h4,
                      const int* __restrict__ gcnt,
                      const uint2* __restrict__ edges_g,
                      const float* __restrict__ w,
                      const float* __restrict__ g,
                      const float* __restrict__ bb,
                      float* __restrict__ out_f32,
                      unsigned int* __restrict__ out_h,
                      int N, int mode) {
    __shared__ uint2 eL[EDGE_CAP];          // 32 KB sorted edge list
    __shared__ int hist[BUCKET_NODES];
    __shared__ int scanb[BUCKET_NODES];
    __shared__ int obase[BUCKET_NODES];
    __shared__ int place[BUCKET_NODES];

    int bkt = blockIdx.x;
    int tid = threadIdx.x;
    int cnt = min(gcnt[bkt], EDGE_CAP);
    const uint2* ep = edges_g + (size_t)bkt * EDGE_CAP;

    if (tid < BUCKET_NODES) hist[tid] = 0;
    __syncthreads();

    // pass 1: stage edges in regs, count per-node
    uint2 ed[8];
    #pragma unroll
    for (int r = 0; r < 8; ++r) {
        int i = r * GT + tid;
        if (i < cnt) {
            uint2 t = ep[i];
            ed[r] = t;
            atomicAdd(&hist[(int)(t.x >> 20)], 1);
        }
    }
    __syncthreads();
    if (tid < BUCKET_NODES) scanb[tid] = hist[tid];
    __syncthreads();
    #pragma unroll
    for (int off = 1; off < BUCKET_NODES; off <<= 1) {
        int v = 0;
        if (tid < BUCKET_NODES && tid >= off) v = scanb[tid - off];
        __syncthreads();
        if (tid < BUCKET_NODES) scanb[tid] += v;
        __syncthreads();
    }
    if (tid < BUCKET_NODES) {
        int ob = scanb[tid] - hist[tid];
        obase[tid] = ob;
        place[tid] = ob;
    }
    __syncthreads();
    // pass 2: scatter into sorted LDS list (order within node irrelevant)
    #pragma unroll
    for (int r = 0; r < 8; ++r) {
        int i = r * GT + tid;
        if (i < cnt) {
            int b = (int)(ed[r].x >> 20);
            int pos = atomicAdd(&place[b], 1);
            eL[pos] = ed[r];
        }
    }
    __syncthreads();

    int wid = tid >> 6, lane = tid & 63, grp = lane >> 4, sl = lane & 15;

    #pragma unroll 1
    for (int k = 0; k < 4; ++k) {
        int ni = k * 32 + wid * 4 + grp;            // 0..127
        int n = (bkt << BUCKET_SHIFT) + ni;
        if (n >= N) continue;
        int st = obase[ni], m = hist[ni];

        float aA0=0,aA1=0,aA2=0,aA3=0, aB0=0,aB1=0,aB2=0,aB3=0;

        #define ACC(H, V)                                                      \
            {   half2_t p;                                                     \
                p = __builtin_bit_cast(half2_t, (H).x);                        \
                aA0 = fmaf((V), (float)p.x, aA0); aB0 = fmaf((V), (float)p.y, aB0); \
                p = __builtin_bit_cast(half2_t, (H).y);                        \
                aA1 = fmaf((V), (float)p.x, aA1); aB1 = fmaf((V), (float)p.y, aB1); \
                p = __builtin_bit_cast(half2_t, (H).z);                        \
                aA2 = fmaf((V), (float)p.x, aA2); aB2 = fmaf((V), (float)p.y, aB2); \
                p = __builtin_bit_cast(half2_t, (H).w);                        \
                aA3 = fmaf((V), (float)p.x, aA3); aB3 = fmaf((V), (float)p.y, aB3); }

        int m4 = m & ~3;
        int j = 0;
        for (; j < m4; j += 4) {                    // 4 in-flight gathers
            uint2 t0 = eL[st + j];
            uint2 t1 = eL[st + j + 1];
            uint2 t2 = eL[st + j + 2];
            uint2 t3 = eL[st + j + 3];
            uint4 h0 = h4[(size_t)(t0.x & 0xfffffu) * 16 + sl];
            uint4 h1 = h4[(size_t)(t1.x & 0xfffffu) * 16 + sl];
            uint4 h2 = h4[(size_t)(t2.x & 0xfffffu) * 16 + sl];
            uint4 h3 = h4[(size_t)(t3.x & 0xfffffu) * 16 + sl];
            float v0 = __uint_as_float(t0.y);
            float v1 = __uint_as_float(t1.y);
            float v2 = __uint_as_float(t2.y);
            float v3 = __uint_as_float(t3.y);
            ACC(h0, v0); ACC(h1, v1); ACC(h2, v2); ACC(h3, v3);
        }
        for (; j < m; ++j) {                        // <=3 tail edges
            uint2 t0 = eL[st + j];
            uint4 h0 = h4[(size_t)(t0.x & 0xfffffu) * 16 + sl];
            float v0 = __uint_as_float(t0.y);
            ACC(h0, v0);
        }
        #undef ACC

        float4 wA = ((const float4*)w)[sl];
        float4 wB = ((const float4*)(w + 64))[sl];
        aA0 *= wA.x; aA1 *= wA.y; aA2 *= wA.z; aA3 *= wA.w;
        aB0 *= wB.x; aB1 *= wB.y; aB2 *= wB.z; aB3 *= wB.w;

        // LN over 128 feats: intra-lane 8 + 4 shfl_xor within the 16-lane group
        float sum = ((aA0 + aA1) + (aA2 + aA3)) + ((aB0 + aB1) + (aB2 + aB3));
        sum += __shfl_xor(sum, 1, 64); sum += __shfl_xor(sum, 2, 64);
        sum += __shfl_xor(sum, 4, 64); sum += __shfl_xor(sum, 8, 64);
        float mu = sum * (1.0f / D);

        float dA0 = aA0 - mu, dA1 = aA1 - mu, dA2 = aA2 - mu, dA3 = aA3 - mu;
        float dB0 = aB0 - mu, dB1 = aB1 - mu, dB2 = aB2 - mu, dB3 = aB3 - mu;
        float sq = ((dA0*dA0 + dA1*dA1) + (dA2*dA2 + dA3*dA3))
                 + ((dB0*dB0 + dB1*dB1) + (dB2*dB2 + dB3*dB3));
        sq += __shfl_xor(sq, 1, 64); sq += __shfl_xor(sq, 2, 64);
        sq += __shfl_xor(sq, 4, 64); sq += __shfl_xor(sq, 8, 64);
        float rstd = rsqrtf(sq * (1.0f / D) + LN_EPS);

        float4 gA = ((const float4*)g)[sl];
        float4 gB = ((const float4*)(g + 64))[sl];
        float4 bA = ((const float4*)bb)[sl];
        float4 bB = ((const float4*)(bb + 64))[sl];

        float oA0 = dA0 * rstd * gA.x + bA.x, oA1 = dA1 * rstd * gA.y + bA.y;
        float oA2 = dA2 * rstd * gA.z + bA.z, oA3 = dA3 * rstd * gA.w + bA.w;
        float oB0 = dB0 * rstd * gB.x + bB.x, oB1 = dB1 * rstd * gB.y + bB.y;
        float oB2 = dB2 * rstd * gB.z + bB.z, oB3 = dB3 * rstd * gB.w + bB.w;

        if (mode == 1) {
            oA0 = fmaxf(oA0, 0.f); oA1 = fmaxf(oA1, 0.f);
            oA2 = fmaxf(oA2, 0.f); oA3 = fmaxf(oA3, 0.f);
            oB0 = fmaxf(oB0, 0.f); oB1 = fmaxf(oB1, 0.f);
            oB2 = fmaxf(oB2, 0.f); oB3 = fmaxf(oB3, 0.f);
            uint4 pw;
            pw.x = pack_h2(oA0, oB0); pw.y = pack_h2(oA1, oB1);
            pw.z = pack_h2(oA2, oB2); pw.w = pack_h2(oA3, oB3);
            ((uint4*)(out_h + (size_t)n * 64))[sl] = pw;
        } else {
            ((float4*)(out_f32 + (size_t)n * D))[sl]      = make_float4(oA0, oA1, oA2, oA3);
            ((float4*)(out_f32 + (size_t)n * D + 64))[sl] = make_float4(oB0, oB1, oB2, oB3);
        }
    }
}

extern "C" void kernel_launch(void* const* d_in, const int* in_sizes, int n_in,
                              void* d_out, int out_size, void* d_ws, size_t ws_size,
                              hipStream_t stream) {
    const float* x    = (const float*)d_in[0];
    const int*   esrc = (const int*)d_in[1];
    const int*   edst = (const int*)d_in[2];
    const float* eval_= (const float*)d_in[3];
    const float* w1   = (const float*)d_in[4];
    const float* w2   = (const float*)d_in[5];
    const float* g1   = (const float*)d_in[6];
    const float* b1   = (const float*)d_in[7];
    const float* g2   = (const float*)d_in[8];
    const float* b2   = (const float*)d_in[9];
    float* out = (float*)d_out;

    const int N = in_sizes[0] / D;   // 100000
    const int E = in_sizes[1];       // 1600000
    const int nbuckets = (N + BUCKET_NODES - 1) >> BUCKET_SHIFT;   // 782

    unsigned int* xb    = (unsigned int*)d_ws;                 // 25.6 MB
    unsigned int* hb    = xb + (size_t)N * 64;                 // 25.6 MB
    uint2*        edges = (uint2*)(hb + (size_t)N * 64);       // 25.6 MB
    int*          gcnt  = (int*)(edges + (size_t)nbuckets * EDGE_CAP);

    const int nwords = N * 64;
    const int conv_blocks = (nwords + FUSE_THREADS - 1) / FUSE_THREADS;
    const int fill_blocks = (E + FUSE_THREADS * K2_EPT - 1) / (FUSE_THREADS * K2_EPT);

    (void)hipMemsetAsync(gcnt, 0, (size_t)nbuckets * sizeof(int), stream);
    conv_fill_kernel<<<conv_blocks + fill_blocks, FUSE_THREADS, 0, stream>>>(
        x, xb, nwords, conv_blocks, esrc, edst, eval_, gcnt, edges, E, nbuckets);
    // layer 1: sort+gather(xb)*w1 -> LN -> ReLU -> hb (f16 split)
    gather_ln_kernel<<<nbuckets, GT, 0, stream>>>((const uint4*)xb, gcnt, edges,
                                                  w1, g1, b1, nullptr, hb, N, 1);
    // layer 2: sort+gather(hb)*w2 -> LN -> out (f32)
    gather_ln_kernel<<<nbuckets, GT, 0, stream>>>((const uint4*)hb, gcnt, edges,
                                                  w2, g2, b2, out, nullptr, N, 0);
}